// Round 12
// baseline (258.937 us; speedup 1.0000x reference)
//
#include <hip/hip_runtime.h>
#include <hip/hip_bf16.h>

// Problem constants
#define IN_DIM 128
#define HID    64
#define NFW    8256     // IN*HID + HID
#define BATCH  256
#define K2     16512    // 2*NFW
#define BM     96       // rows per m-block (8256 = 86*96)
#define NMB    86
#define KSPLIT 6        // 129 BK128-tiles = 3 splits x 22 + 3 x 21
#define GRID_M 516      // NMB * KSPLIT; 3 blocks/CU capacity -> 1 generation

typedef float f32x4 __attribute__((ext_vector_type(4)));
typedef short bf16x8 __attribute__((ext_vector_type(8)));

__device__ __forceinline__ unsigned int f2bf(float f) {
    union { float f; unsigned int u; } v; v.f = f;
    return (v.u + 0x7FFFu + ((v.u >> 16) & 1u)) >> 16;   // RNE f32->bf16 (bits)
}

// ---------------------------------------------------------------------------
// Kernel 0: W1 (16512x128 f32) -> W1T tiled bf16. Tile kt: [128 n][64 kl].
// ---------------------------------------------------------------------------
__global__ __launch_bounds__(256) void k_prep_w1t(const float* __restrict__ W1,
                                                  unsigned short* __restrict__ W1T) {
    __shared__ float tile[64][IN_DIM + 1];
    const int kt = blockIdx.x;               // 0..257
    const int t  = threadIdx.x;
    const float* src = W1 + (size_t)kt * 64 * IN_DIM;
#pragma unroll
    for (int p = 0; p < 8; ++p) {
        int c4 = p * 256 + t;
        int e = c4 * 4;
        int row = e >> 7, col = e & 127;
        f32x4 v = *reinterpret_cast<const f32x4*>(src + row * IN_DIM + col);
        tile[row][col+0] = v.x; tile[row][col+1] = v.y;
        tile[row][col+2] = v.z; tile[row][col+3] = v.w;
    }
    __syncthreads();
    unsigned short* dst = W1T + (size_t)kt * (IN_DIM * 64);
#pragma unroll
    for (int it = 0; it < 4; ++it) {
        int c = it * 256 + t;
        int n = c >> 3, kl0 = (c & 7) * 8;
        uint4 w;
        w.x = f2bf(tile[kl0+0][n]) | (f2bf(tile[kl0+1][n]) << 16);
        w.y = f2bf(tile[kl0+2][n]) | (f2bf(tile[kl0+3][n]) << 16);
        w.z = f2bf(tile[kl0+4][n]) | (f2bf(tile[kl0+5][n]) << 16);
        w.w = f2bf(tile[kl0+6][n]) | (f2bf(tile[kl0+7][n]) << 16);
        *reinterpret_cast<uint4*>(dst + c * 8) = w;
    }
}

// ---------------------------------------------------------------------------
// Kernel 1: split-K GEMM, BK=128 per load-phase (512B contiguous per row ->
// half the DRAM page-opens of BK=64; R7-R11 showed gemm pinned at ~3.7TB/s
// across all scheduling changes => pattern-bound, not schedule-bound).
// B-fragments load DIRECT from L2-resident W1T (no B LDS; pattern proven in
// k_uchains). A: 12 named f32x4 staging regs -> cvt bf16 -> 24KB dbuf LDS.
// 48KB LDS -> 3 blocks/CU -> grid 516 in one generation. LBAR lgkmcnt-only.
// ---------------------------------------------------------------------------
__global__ __launch_bounds__(256, 3) void k_gemm_M(const float* __restrict__ W2,
                                                   const unsigned short* __restrict__ W1T,
                                                   float* __restrict__ Mpart) {
    __shared__ __align__(16) unsigned char smem[49152];  // A dbuf: 2 x [96][256B]
    float* trs = reinterpret_cast<float*>(smem);         // [48][132] epilogue alias

    const int t = threadIdx.x;
    const int lane = t & 63, wid = t >> 6;
    const int wm = wid >> 1, wn = wid & 1;    // wave grid 2m x 2n
    const int l15 = lane & 15, l4 = (lane >> 4) & 3;

    // bijective blockIdx -> (ks, mb). 516 = 4*65 + 4*64 across 8 XCDs.
    const int b = blockIdx.x;
    const int xcd = b & 7, slot = b >> 3;
    const int p = (xcd < 4) ? (xcd * 65 + slot) : (260 + (xcd - 4) * 64 + slot);
    const int ks = p / NMB, mb = p % NMB;

    const int m0 = mb * BM;
    // non-uniform split: ks 0..2 -> 22 pairs, ks 3..5 -> 21; 3*22+3*21=129
    const int NT  = (ks < 3) ? 22 : 21;
    const int g0p = ks * 21 + ((ks < 3) ? ks : 3);
    const int kt0 = (p * 5) % NT;             // stagger (fp32 acc: safe)

    // A staging: 8 threads per row-chunk; thread covers 64B (16 f32);
    // 3 passes of 32 rows. 512B/row contiguous per load-phase.
    const int ar  = t >> 3;                   // base row 0..31
    const int asw = (ar & 7) << 4;
    const float* abase = W2 + (size_t)(m0 + ar) * K2 + (t & 7) * 16;
    // B per-lane offset inside a W1T tile ([128 n][64 kl] bf16)
    const int boff = (wn * 64 + l15) * 64 + l4 * 8;

    f32x4 sa0, sa1, sa2, sa3, sa4, sa5, sa6, sa7, sa8, sa9, sa10, sa11;
    f32x4 acc[3][4];
#pragma unroll
    for (int mf = 0; mf < 3; ++mf)
#pragma unroll
        for (int nf = 0; nf < 4; ++nf)
            acc[mf][nf] = (f32x4){0.f, 0.f, 0.f, 0.f};

#define LOADA(GP) {                                                            \
    const float* _a0 = abase + (size_t)(GP) * 128;                             \
    sa0  = *reinterpret_cast<const f32x4*>(_a0);                               \
    sa1  = *reinterpret_cast<const f32x4*>(_a0 + 4);                           \
    sa2  = *reinterpret_cast<const f32x4*>(_a0 + 8);                           \
    sa3  = *reinterpret_cast<const f32x4*>(_a0 + 12);                          \
    const float* _a1 = _a0 + (size_t)32 * K2;                                  \
    sa4  = *reinterpret_cast<const f32x4*>(_a1);                               \
    sa5  = *reinterpret_cast<const f32x4*>(_a1 + 4);                           \
    sa6  = *reinterpret_cast<const f32x4*>(_a1 + 8);                           \
    sa7  = *reinterpret_cast<const f32x4*>(_a1 + 12);                          \
    const float* _a2 = _a0 + (size_t)64 * K2;                                  \
    sa8  = *reinterpret_cast<const f32x4*>(_a2);                               \
    sa9  = *reinterpret_cast<const f32x4*>(_a2 + 4);                           \
    sa10 = *reinterpret_cast<const f32x4*>(_a2 + 8);                           \
    sa11 = *reinterpret_cast<const f32x4*>(_a2 + 12); }

#define PK(A,B) (f2bf(A) | (f2bf(B) << 16))
#define STPASS(BASE, ROW, LO0, LO1, HI0, HI1) {                                \
    uint4 _w0, _w1;                                                            \
    _w0.x = PK(LO0.x, LO0.y); _w0.y = PK(LO0.z, LO0.w);                        \
    _w0.z = PK(LO1.x, LO1.y); _w0.w = PK(LO1.z, LO1.w);                        \
    _w1.x = PK(HI0.x, HI0.y); _w1.y = PK(HI0.z, HI0.w);                        \
    _w1.z = PK(HI1.x, HI1.y); _w1.w = PK(HI1.z, HI1.w);                        \
    const int _c = (t & 7) * 32;                                               \
    *reinterpret_cast<uint4*>(&(BASE)[(ROW) * 256 + ((_c)      ^ asw)]) = _w0; \
    *reinterpret_cast<uint4*>(&(BASE)[(ROW) * 256 + ((_c + 16) ^ asw)]) = _w1; }

#define STOREA(BUF) {                                                          \
    unsigned char* _Ash = smem + (BUF) * 24576;                                \
    STPASS(_Ash, ar,      sa0, sa1, sa2,  sa3);                                \
    STPASS(_Ash, ar + 32, sa4, sa5, sa6,  sa7);                                \
    STPASS(_Ash, ar + 64, sa8, sa9, sa10, sa11); }

#define MFMA_PAIR(BUF, GP) {                                                   \
    const unsigned char* _Ash = smem + (BUF) * 24576;                          \
    _Pragma("unroll")                                                          \
    for (int kk = 0; kk < 4; ++kk) {                                           \
        const unsigned short* _bp = W1T + (size_t)(2 * (GP) + (kk >> 1)) * 8192\
                                    + boff + (kk & 1) * 32;                    \
        bf16x8 bf0 = *reinterpret_cast<const bf16x8*>(_bp);                    \
        bf16x8 bf1 = *reinterpret_cast<const bf16x8*>(_bp + 1024);             \
        bf16x8 bf2 = *reinterpret_cast<const bf16x8*>(_bp + 2048);             \
        bf16x8 bf3 = *reinterpret_cast<const bf16x8*>(_bp + 3072);             \
        const int _fc = kk * 64 + l4 * 16;                                     \
        const int _r0 = wm * 48 + l15;                                         \
        bf16x8 af0 = *reinterpret_cast<const bf16x8*>(                         \
            &_Ash[(_r0)      * 256 + (_fc ^ (((_r0)      & 7) << 4))]);        \
        bf16x8 af1 = *reinterpret_cast<const bf16x8*>(                         \
            &_Ash[(_r0 + 16) * 256 + (_fc ^ (((_r0 + 16) & 7) << 4))]);        \
        bf16x8 af2 = *reinterpret_cast<const bf16x8*>(                         \
            &_Ash[(_r0 + 32) * 256 + (_fc ^ (((_r0 + 32) & 7) << 4))]);        \
        acc[0][0] = __builtin_amdgcn_mfma_f32_16x16x32_bf16(af0, bf0, acc[0][0], 0, 0, 0); \
        acc[0][1] = __builtin_amdgcn_mfma_f32_16x16x32_bf16(af0, bf1, acc[0][1], 0, 0, 0); \
        acc[0][2] = __builtin_amdgcn_mfma_f32_16x16x32_bf16(af0, bf2, acc[0][2], 0, 0, 0); \
        acc[0][3] = __builtin_amdgcn_mfma_f32_16x16x32_bf16(af0, bf3, acc[0][3], 0, 0, 0); \
        acc[1][0] = __builtin_amdgcn_mfma_f32_16x16x32_bf16(af1, bf0, acc[1][0], 0, 0, 0); \
        acc[1][1] = __builtin_amdgcn_mfma_f32_16x16x32_bf16(af1, bf1, acc[1][1], 0, 0, 0); \
        acc[1][2] = __builtin_amdgcn_mfma_f32_16x16x32_bf16(af1, bf2, acc[1][2], 0, 0, 0); \
        acc[1][3] = __builtin_amdgcn_mfma_f32_16x16x32_bf16(af1, bf3, acc[1][3], 0, 0, 0); \
        acc[2][0] = __builtin_amdgcn_mfma_f32_16x16x32_bf16(af2, bf0, acc[2][0], 0, 0, 0); \
        acc[2][1] = __builtin_amdgcn_mfma_f32_16x16x32_bf16(af2, bf1, acc[2][1], 0, 0, 0); \
        acc[2][2] = __builtin_amdgcn_mfma_f32_16x16x32_bf16(af2, bf2, acc[2][2], 0, 0, 0); \
        acc[2][3] = __builtin_amdgcn_mfma_f32_16x16x32_bf16(af2, bf3, acc[2][3], 0, 0, 0); \
    } }

#define LBAR() { asm volatile("s_waitcnt lgkmcnt(0)" ::: "memory");            \
                 __builtin_amdgcn_s_barrier();                                 \
                 __builtin_amdgcn_sched_barrier(0); }

    // prologue: pair kt0 -> buf0; issue kt0+1
    int kc = kt0;                                     // compute walker
    int klw = kt0 + 2 >= NT ? kt0 + 2 - NT : kt0 + 2; // load walker (pos i+2)
    LOADA(g0p + kc);
    STOREA(0);
    { int kn = kt0 + 1; if (kn >= NT) kn -= NT; LOADA(g0p + kn); }
    LBAR();

    int cur = 0;
#pragma unroll 1
    for (int i = 0; i < NT; ++i) {
        if (i + 1 < NT) {
            STOREA(cur ^ 1);                  // regs = pair i+1 (landed)
        }
        if (i + 2 < NT) {
            LOADA(g0p + klw);                 // issue pair i+2 (512B/row)
            klw = klw + 1 >= NT ? 0 : klw + 1;
        }
        MFMA_PAIR(cur, g0p + kc);             // pair i (B direct from L2)
        kc = kc + 1 >= NT ? 0 : kc + 1;
        LBAR();
        cur ^= 1;
    }

    // Epilogue: 2 rounds (wm groups); transpose via trs -> coalesced stores
    float* outp = Mpart + (size_t)ks * ((size_t)NFW * IN_DIM) + (size_t)m0 * IN_DIM;
#pragma unroll 1
    for (int w = 0; w < 2; ++w) {
        __syncthreads();
        if (wm == w) {
#pragma unroll
            for (int mf = 0; mf < 3; ++mf)
#pragma unroll
                for (int nf = 0; nf < 4; ++nf)
#pragma unroll
                    for (int r = 0; r < 4; ++r)
                        trs[(mf * 16 + l4 * 4 + r) * 132 + wn * 64 + nf * 16 + l15] = acc[mf][nf][r];
        }
        __syncthreads();
#pragma unroll
        for (int q = 0; q < 6; ++q) {
            int idx = q * 256 + t;            // 0..1535 (48 rows x 32 f32x4)
            int rr = idx >> 5, c4 = (idx & 31) << 2;
            f32x4 v = *reinterpret_cast<const f32x4*>(&trs[rr * 132 + c4]);
            *reinterpret_cast<f32x4*>(outp + (size_t)(w * 48 + rr) * IN_DIM + c4) = v;
        }
    }
#undef LOADA
#undef PK
#undef STPASS
#undef STOREA
#undef MFMA_PAIR
#undef LBAR
}

// ---------------------------------------------------------------------------
// Kernel 1b: reduce 6 partials -> M bf16. 264,192 f32x4 chunks.
// ---------------------------------------------------------------------------
__global__ __launch_bounds__(256) void k_reduce_M(const float* __restrict__ Mpart,
                                                  unsigned short* __restrict__ Mb) {
    const int idx = blockIdx.x * 256 + threadIdx.x;
    f32x4 s = (f32x4){0.f, 0.f, 0.f, 0.f};
#pragma unroll
    for (int ks = 0; ks < KSPLIT; ++ks) {
        f32x4 v = *reinterpret_cast<const f32x4*>(
            Mpart + (size_t)ks * ((size_t)NFW * IN_DIM) + (size_t)idx * 4);
        s.x += v.x; s.y += v.y; s.z += v.z; s.w += v.w;
    }
    uint2 o;
    o.x = f2bf(s.x) | (f2bf(s.y) << 16);
    o.y = f2bf(s.z) | (f2bf(s.w) << 16);
    *reinterpret_cast<uint2*>(Mb + (size_t)idx * 4) = o;
}

// ---------------------------------------------------------------------------
// Kernel 2 (fused U + chains): block = one 64-j slice. Phase 1: 4 waves
// compute U[256 i][64 j] into LDS; Phase 2: wave 0 runs the 64 sigmoid
// chains from LDS, streaming FW to HBM.
// ---------------------------------------------------------------------------
__global__ __launch_bounds__(256) void k_uchains(const float* __restrict__ xs,
                                                 const unsigned short* __restrict__ Mb,
                                                 const float* __restrict__ fw0,
                                                 float* __restrict__ FW) {
    __shared__ float Ulds[256][68];           // +4 pad
    const int t = threadIdx.x, lane = t & 63, wid = t >> 6;
    const int l15 = lane & 15, l4 = (lane >> 4) & 3;
    const int j0 = blockIdx.x * 64;

    bf16x8 bfr[4][4];                         // [kk][nf], static-indexed
#pragma unroll
    for (int kk = 0; kk < 4; ++kk)
#pragma unroll
        for (int nf = 0; nf < 4; ++nf)
            bfr[kk][nf] = *reinterpret_cast<const bf16x8*>(
                Mb + (size_t)(j0 + nf * 16 + l15) * IN_DIM + kk * 32 + l4 * 8);

#pragma unroll 1
    for (int ib = 0; ib < 4; ++ib) {
        const int i0 = wid * 64 + ib * 16;
        f32x4 acc[4];
#pragma unroll
        for (int nf = 0; nf < 4; ++nf) acc[nf] = (f32x4){0.f, 0.f, 0.f, 0.f};
#pragma unroll
        for (int kk = 0; kk < 4; ++kk) {
            const float* xp = xs + (size_t)(i0 + l15) * IN_DIM + kk * 32 + l4 * 8;
            f32x4 x0 = *reinterpret_cast<const f32x4*>(xp);
            f32x4 x1 = *reinterpret_cast<const f32x4*>(xp + 4);
            union { bf16x8 v; unsigned short s[8]; } af;
            af.s[0] = f2bf(x0.x); af.s[1] = f2bf(x0.y);
            af.s[2] = f2bf(x0.z); af.s[3] = f2bf(x0.w);
            af.s[4] = f2bf(x1.x); af.s[5] = f2bf(x1.y);
            af.s[6] = f2bf(x1.z); af.s[7] = f2bf(x1.w);
#pragma unroll
            for (int nf = 0; nf < 4; ++nf)
                acc[nf] = __builtin_amdgcn_mfma_f32_16x16x32_bf16(af.v, bfr[kk][nf], acc[nf], 0, 0, 0);
        }
#pragma unroll
        for (int nf = 0; nf < 4; ++nf)
#pragma unroll
            for (int r = 0; r < 4; ++r)
                Ulds[i0 + l4 * 4 + r][nf * 16 + l15] = acc[nf][r];
    }
    __syncthreads();

    if (wid == 0) {
        const int j = j0 + lane;
        float fw = fw0[j];
        float* fp = FW + j;
#pragma unroll 8
        for (int i = 0; i < BATCH; ++i) {
            float u = Ulds[i][lane];
            float z = 10.0f * (fw + u - 0.5f);
            fw = 1.0f / (1.0f + __expf(-z));
            fp[(size_t)i * NFW] = fw;
        }
    }
}

// ---------------------------------------------------------------------------
// Kernel 4: preds. Block per i: h = relu(fw1 @ xs_i), out[i] = fw2 . h.
// ---------------------------------------------------------------------------
__global__ __launch_bounds__(256) void k_preds(const float* __restrict__ FW,
                                               const float* __restrict__ xs,
                                               float* __restrict__ out) {
    __shared__ float xsh[IN_DIM];
    __shared__ float hsh[HID];
    const int i = blockIdx.x, t = threadIdx.x;
    if (t < 32) {
        f32x4 v = *reinterpret_cast<const f32x4*>(xs + (size_t)i * IN_DIM + t * 4);
        xsh[t*4+0] = v.x; xsh[t*4+1] = v.y; xsh[t*4+2] = v.z; xsh[t*4+3] = v.w;
    }
    __syncthreads();
    const int k = t >> 2, q = t & 3;
    const float* fr = FW + (size_t)i * NFW + k * IN_DIM + q * 32;
    float p = 0.f;
#pragma unroll
    for (int m = 0; m < 8; ++m) {
        f32x4 v = *reinterpret_cast<const f32x4*>(fr + m * 4);
        const int d = q * 32 + m * 4;
        p += v.x * xsh[d] + v.y * xsh[d+1] + v.z * xsh[d+2] + v.w * xsh[d+3];
    }
    p += __shfl_xor(p, 1);
    p += __shfl_xor(p, 2);
    if (q == 0) hsh[k] = fmaxf(p, 0.f);
    __syncthreads();
    if (t < 64) {
        float v = FW[(size_t)i * NFW + IN_DIM * HID + t] * hsh[t];
        v += __shfl_xor(v, 1);  v += __shfl_xor(v, 2);  v += __shfl_xor(v, 4);
        v += __shfl_xor(v, 8);  v += __shfl_xor(v, 16); v += __shfl_xor(v, 32);
        if (t == 0) out[i] = v;
    }
}

// ---------------------------------------------------------------------------
// Workspace layout (~40.2 MiB):
//   W1T  bf16 :  4,227,072 B @ 0
//   Mpart f32 : 25,362,432 B @  4,227,072   (6 x 8256 x 128)
//   Mb   bf16 :  2,113,536 B @ 29,589,504
//   FW   f32  :  8,454,144 B @ 31,703,040
// ---------------------------------------------------------------------------
extern "C" void kernel_launch(void* const* d_in, const int* in_sizes, int n_in,
                              void* d_out, int out_size, void* d_ws, size_t ws_size,
                              hipStream_t stream) {
    const float* x   = (const float*)d_in[0];   // (256,1,128)
    const float* W1  = (const float*)d_in[1];   // (16512,128)
    const float* W2  = (const float*)d_in[2];   // (8256,16512)
    const float* fw0 = (const float*)d_in[3];   // (8256,)
    float* out = (float*)d_out;                 // 256 f32

    char* ws = (char*)d_ws;
    unsigned short* W1T   = (unsigned short*)(ws);
    float*          Mpart = (float*)(ws + 4227072);
    unsigned short* Mb    = (unsigned short*)(ws + 29589504);
    float*          FW    = (float*)(ws + 31703040);

    hipLaunchKernelGGL(k_prep_w1t, dim3(258),    dim3(256), 0, stream, W1, W1T);
    hipLaunchKernelGGL(k_gemm_M,   dim3(GRID_M), dim3(256), 0, stream, W2, W1T, Mpart);
    hipLaunchKernelGGL(k_reduce_M, dim3(1032),   dim3(256), 0, stream, Mpart, Mb);
    hipLaunchKernelGGL(k_uchains,  dim3(129),    dim3(256), 0, stream, x, Mb, fw0, FW);
    hipLaunchKernelGGL(k_preds,    dim3(256),    dim3(256), 0, stream, FW, x, out);
}

// Round 13
// 183.976 us; speedup vs baseline: 1.4075x; 1.4075x over previous
//
#include <hip/hip_runtime.h>
#include <hip/hip_bf16.h>

// Problem constants
#define IN_DIM 128
#define HID    64
#define NFW    8256     // IN*HID + HID
#define BATCH  256
#define K2     16512    // 2*NFW
#define BM     96       // rows per m-block (8256 = 86*96)
#define NMB    86
#define KSPLIT 6
#define NT_PER 43       // k-tiles (of 64) per split; 6*43 = 258
#define GRID_M 516      // NMB * KSPLIT

typedef float f32x4 __attribute__((ext_vector_type(4)));
typedef short bf16x8 __attribute__((ext_vector_type(8)));

__device__ __forceinline__ unsigned int f2bf(float f) {
    union { float f; unsigned int u; } v; v.f = f;
    return (v.u + 0x7FFFu + ((v.u >> 16) & 1u)) >> 16;   // RNE f32->bf16 (bits)
}

// ---------------------------------------------------------------------------
// Kernel 0: W1 (16512x128 f32) -> W1T tiled bf16. Tile kt: [128 n][64 kl].
// ---------------------------------------------------------------------------
__global__ __launch_bounds__(256) void k_prep_w1t(const float* __restrict__ W1,
                                                  unsigned short* __restrict__ W1T) {
    __shared__ float tile[64][IN_DIM + 1];
    const int kt = blockIdx.x;               // 0..257
    const int t  = threadIdx.x;
    const float* src = W1 + (size_t)kt * 64 * IN_DIM;
#pragma unroll
    for (int p = 0; p < 8; ++p) {
        int c4 = p * 256 + t;
        int e = c4 * 4;
        int row = e >> 7, col = e & 127;
        f32x4 v = *reinterpret_cast<const f32x4*>(src + row * IN_DIM + col);
        tile[row][col+0] = v.x; tile[row][col+1] = v.y;
        tile[row][col+2] = v.z; tile[row][col+3] = v.w;
    }
    __syncthreads();
    unsigned short* dst = W1T + (size_t)kt * (IN_DIM * 64);
#pragma unroll
    for (int it = 0; it < 4; ++it) {
        int c = it * 256 + t;
        int n = c >> 3, kl0 = (c & 7) * 8;
        uint4 w;
        w.x = f2bf(tile[kl0+0][n]) | (f2bf(tile[kl0+1][n]) << 16);
        w.y = f2bf(tile[kl0+2][n]) | (f2bf(tile[kl0+3][n]) << 16);
        w.z = f2bf(tile[kl0+4][n]) | (f2bf(tile[kl0+5][n]) << 16);
        w.w = f2bf(tile[kl0+6][n]) | (f2bf(tile[kl0+7][n]) << 16);
        *reinterpret_cast<uint4*>(dst + c * 8) = w;
    }
}

// ---------------------------------------------------------------------------
// Kernel 1: split-K GEMM, BM=96 (exact R11 structure: B staged in LDS,
// XOR swizzle conflict-free, XCD k-split grouping, stagger, named regs,
// (256,2) no-spill, dbuf LDS + lgkmcnt-only barrier) with ONE change:
// loop body reordered MFMA-FIRST. The vmcnt wait on tile i+1's staged
// loads now sits AFTER the ~3Kcy MFMA+LDS-read phase instead of first
// after the barrier — loads get a full extra phase to land, smoothing
// the bursty HBM duty (R7-R11: pinned ~57%). sched_barrier(0) pins the
// order against compiler hoisting.
// ---------------------------------------------------------------------------
__global__ __launch_bounds__(256, 2) void k_gemm_M(const float* __restrict__ W2,
                                                   const unsigned short* __restrict__ W1T,
                                                   float* __restrict__ Mpart) {
    __shared__ __align__(16) unsigned char smem[57344];  // A:2x12K @0, B:2x16K @24K
    float* trs = reinterpret_cast<float*>(smem);         // [48][132] epilogue alias

    const int t = threadIdx.x;
    const int lane = t & 63, wid = t >> 6;
    const int wm = wid >> 1, wn = wid & 1;    // wave grid 2m x 2n
    const int l15 = lane & 15, l4 = (lane >> 4) & 3;

    // bijective blockIdx -> (ks, mb); 516 = 4*65 + 4*64 across 8 XCDs.
    const int b = blockIdx.x;
    const int xcd = b & 7, slot = b >> 3;
    const int p = (xcd < 4) ? (xcd * 65 + slot) : (260 + (xcd - 4) * 64 + slot);
    const int ks = p / NMB, mb = p % NMB;

    const int m0 = mb * BM;
    const int g0 = ks * NT_PER;
    const int kt0 = (p * 7) % NT_PER;         // K-phase stagger (fp32 acc: safe)

    // A staging: 8 threads per 64-f32 row-chunk; thread covers 32B (8 f32).
    // 3 passes of 32 rows (row = (t>>3) + 32*pass).
    const int ar  = t >> 3;                   // base row 0..31
    const int asw = (ar & 7) << 4;            // (row&7) invariant across passes
    const float* abase = W2 + (size_t)(m0 + ar) * K2 + (size_t)g0 * 64 + (t & 7) * 8;
    // B staging: 2 threads per 128-B row; lane covers 64 B (32 bf16)
    const int bn  = t >> 1;                   // row 0..127
    const int bsw = (bn & 7) << 4;
    const unsigned short* bbase = W1T + (size_t)g0 * 8192 + bn * 64 + (t & 1) * 32;

    // named staging regs (anti-spill)
    f32x4 sa0, sa1, sa2, sa3, sa4, sa5;       // 3 passes x 2
    uint4 sb0, sb1, sb2, sb3;
    f32x4 acc[3][4];
#pragma unroll
    for (int mf = 0; mf < 3; ++mf)
#pragma unroll
        for (int nf = 0; nf < 4; ++nf)
            acc[mf][nf] = (f32x4){0.f, 0.f, 0.f, 0.f};

#define LOADREGS(KT) {                                                         \
    const float* _ap = abase + (size_t)(KT) * 64;                              \
    sa0 = *reinterpret_cast<const f32x4*>(_ap);                                \
    sa1 = *reinterpret_cast<const f32x4*>(_ap + 4);                            \
    sa2 = *reinterpret_cast<const f32x4*>(_ap + (size_t)32 * K2);              \
    sa3 = *reinterpret_cast<const f32x4*>(_ap + (size_t)32 * K2 + 4);          \
    sa4 = *reinterpret_cast<const f32x4*>(_ap + (size_t)64 * K2);              \
    sa5 = *reinterpret_cast<const f32x4*>(_ap + (size_t)64 * K2 + 4);          \
    const unsigned short* _bp = bbase + (size_t)(KT) * 8192;                   \
    sb0 = *reinterpret_cast<const uint4*>(_bp);                                \
    sb1 = *reinterpret_cast<const uint4*>(_bp + 8);                            \
    sb2 = *reinterpret_cast<const uint4*>(_bp + 16);                           \
    sb3 = *reinterpret_cast<const uint4*>(_bp + 24); }

#define CVT16(W, LO, HI) { W.x = f2bf(LO.x) | (f2bf(LO.y) << 16);              \
                           W.y = f2bf(LO.z) | (f2bf(LO.w) << 16);              \
                           W.z = f2bf(HI.x) | (f2bf(HI.y) << 16);              \
                           W.w = f2bf(HI.z) | (f2bf(HI.w) << 16); }

#define STOREREGS(BUF) {                                                       \
    unsigned char* _Ash = smem + (BUF) * 12288;                                \
    unsigned char* _Bsh = smem + 24576 + (BUF) * 16384;                        \
    uint4 _w;                                                                  \
    const int _abyte = (t & 7) * 16;                                           \
    CVT16(_w, sa0, sa1);                                                       \
    *reinterpret_cast<uint4*>(&_Ash[(ar)      * 128 + (_abyte ^ asw)]) = _w;   \
    CVT16(_w, sa2, sa3);                                                       \
    *reinterpret_cast<uint4*>(&_Ash[(ar + 32) * 128 + (_abyte ^ asw)]) = _w;   \
    CVT16(_w, sa4, sa5);                                                       \
    *reinterpret_cast<uint4*>(&_Ash[(ar + 64) * 128 + (_abyte ^ asw)]) = _w;   \
    const int _bb = (t & 1) * 64;                                              \
    *reinterpret_cast<uint4*>(&_Bsh[bn * 128 + ((_bb)      ^ bsw)]) = sb0;     \
    *reinterpret_cast<uint4*>(&_Bsh[bn * 128 + ((_bb + 16) ^ bsw)]) = sb1;     \
    *reinterpret_cast<uint4*>(&_Bsh[bn * 128 + ((_bb + 32) ^ bsw)]) = sb2;     \
    *reinterpret_cast<uint4*>(&_Bsh[bn * 128 + ((_bb + 48) ^ bsw)]) = sb3; }

#define MFMA_PHASE(BUF) {                                                      \
    const unsigned char* _Ash = smem + (BUF) * 12288;                          \
    const unsigned char* _Bsh = smem + 24576 + (BUF) * 16384;                  \
    const int _fsw = (l15 & 7) << 4;                                           \
    _Pragma("unroll")                                                          \
    for (int kk = 0; kk < 2; ++kk) {                                           \
        const int _fc = (kk * 64 + l4 * 16) ^ _fsw;                            \
        bf16x8 af0 = *reinterpret_cast<const bf16x8*>(                         \
            &_Ash[(wm * 48 +  0 + l15) * 128 + _fc]);                          \
        bf16x8 af1 = *reinterpret_cast<const bf16x8*>(                         \
            &_Ash[(wm * 48 + 16 + l15) * 128 + _fc]);                          \
        bf16x8 af2 = *reinterpret_cast<const bf16x8*>(                         \
            &_Ash[(wm * 48 + 32 + l15) * 128 + _fc]);                          \
        bf16x8 bf0 = *reinterpret_cast<const bf16x8*>(                         \
            &_Bsh[(wn * 64 +  0 + l15) * 128 + _fc]);                          \
        bf16x8 bf1 = *reinterpret_cast<const bf16x8*>(                         \
            &_Bsh[(wn * 64 + 16 + l15) * 128 + _fc]);                          \
        bf16x8 bf2 = *reinterpret_cast<const bf16x8*>(                         \
            &_Bsh[(wn * 64 + 32 + l15) * 128 + _fc]);                          \
        bf16x8 bf3 = *reinterpret_cast<const bf16x8*>(                         \
            &_Bsh[(wn * 64 + 48 + l15) * 128 + _fc]);                          \
        acc[0][0] = __builtin_amdgcn_mfma_f32_16x16x32_bf16(af0, bf0, acc[0][0], 0, 0, 0); \
        acc[0][1] = __builtin_amdgcn_mfma_f32_16x16x32_bf16(af0, bf1, acc[0][1], 0, 0, 0); \
        acc[0][2] = __builtin_amdgcn_mfma_f32_16x16x32_bf16(af0, bf2, acc[0][2], 0, 0, 0); \
        acc[0][3] = __builtin_amdgcn_mfma_f32_16x16x32_bf16(af0, bf3, acc[0][3], 0, 0, 0); \
        acc[1][0] = __builtin_amdgcn_mfma_f32_16x16x32_bf16(af1, bf0, acc[1][0], 0, 0, 0); \
        acc[1][1] = __builtin_amdgcn_mfma_f32_16x16x32_bf16(af1, bf1, acc[1][1], 0, 0, 0); \
        acc[1][2] = __builtin_amdgcn_mfma_f32_16x16x32_bf16(af1, bf2, acc[1][2], 0, 0, 0); \
        acc[1][3] = __builtin_amdgcn_mfma_f32_16x16x32_bf16(af1, bf3, acc[1][3], 0, 0, 0); \
        acc[2][0] = __builtin_amdgcn_mfma_f32_16x16x32_bf16(af2, bf0, acc[2][0], 0, 0, 0); \
        acc[2][1] = __builtin_amdgcn_mfma_f32_16x16x32_bf16(af2, bf1, acc[2][1], 0, 0, 0); \
        acc[2][2] = __builtin_amdgcn_mfma_f32_16x16x32_bf16(af2, bf2, acc[2][2], 0, 0, 0); \
        acc[2][3] = __builtin_amdgcn_mfma_f32_16x16x32_bf16(af2, bf3, acc[2][3], 0, 0, 0); \
    } }

#define LBAR() { asm volatile("s_waitcnt lgkmcnt(0)" ::: "memory");            \
                 __builtin_amdgcn_s_barrier();                                 \
                 __builtin_amdgcn_sched_barrier(0); }

    // prologue: tile kt0 -> buf0; issue kt0+1
    int kreg = kt0;
    LOADREGS(kreg);
    STOREREGS(0);
    { int kn = kreg + 1; if (kn >= NT_PER) kn = 0; kreg = kn; }
    LOADREGS(kreg);
    LBAR();

    int cur = 0;
#pragma unroll 1
    for (int i = 0; i < NT_PER; ++i) {
        MFMA_PHASE(cur);                      // tile i — compute FIRST
        __builtin_amdgcn_sched_barrier(0);    // pin: vmcnt wait stays below
        if (i + 1 < NT_PER) {
            STOREREGS(cur ^ 1);               // tile i+1 (vmcnt wait here,
        }                                     //  after a full MFMA phase)
        if (i + 2 < NT_PER) {
            int kn = kreg + 1; if (kn >= NT_PER) kn = 0; kreg = kn;
            LOADREGS(kreg);                   // issue tile i+2
        }
        LBAR();
        cur ^= 1;
    }

    // Epilogue: 2 rounds (wm groups); transpose via trs -> coalesced stores
    float* outp = Mpart + (size_t)ks * ((size_t)NFW * IN_DIM) + (size_t)m0 * IN_DIM;
#pragma unroll 1
    for (int w = 0; w < 2; ++w) {
        __syncthreads();
        if (wm == w) {
#pragma unroll
            for (int mf = 0; mf < 3; ++mf)
#pragma unroll
                for (int nf = 0; nf < 4; ++nf)
#pragma unroll
                    for (int r = 0; r < 4; ++r)
                        trs[(mf * 16 + l4 * 4 + r) * 132 + wn * 64 + nf * 16 + l15] = acc[mf][nf][r];
        }
        __syncthreads();
#pragma unroll
        for (int q = 0; q < 6; ++q) {
            int idx = q * 256 + t;            // 0..1535 (48 rows x 32 f32x4)
            int rr = idx >> 5, c4 = (idx & 31) << 2;
            f32x4 v = *reinterpret_cast<const f32x4*>(&trs[rr * 132 + c4]);
            *reinterpret_cast<f32x4*>(outp + (size_t)(w * 48 + rr) * IN_DIM + c4) = v;
        }
    }
#undef LOADREGS
#undef CVT16
#undef STOREREGS
#undef MFMA_PHASE
#undef LBAR
}

// ---------------------------------------------------------------------------
// Kernel 1b: reduce 6 partials -> M bf16. 264,192 f32x4 chunks.
// ---------------------------------------------------------------------------
__global__ __launch_bounds__(256) void k_reduce_M(const float* __restrict__ Mpart,
                                                  unsigned short* __restrict__ Mb) {
    const int idx = blockIdx.x * 256 + threadIdx.x;
    f32x4 s = (f32x4){0.f, 0.f, 0.f, 0.f};
#pragma unroll
    for (int ks = 0; ks < KSPLIT; ++ks) {
        f32x4 v = *reinterpret_cast<const f32x4*>(
            Mpart + (size_t)ks * ((size_t)NFW * IN_DIM) + (size_t)idx * 4);
        s.x += v.x; s.y += v.y; s.z += v.z; s.w += v.w;
    }
    uint2 o;
    o.x = f2bf(s.x) | (f2bf(s.y) << 16);
    o.y = f2bf(s.z) | (f2bf(s.w) << 16);
    *reinterpret_cast<uint2*>(Mb + (size_t)idx * 4) = o;
}

// ---------------------------------------------------------------------------
// Kernel 2 (fused U + chains): block = one 64-j slice. Phase 1: 4 waves
// compute U[256 i][64 j] into LDS; Phase 2: wave 0 runs the 64 sigmoid
// chains from LDS, streaming FW to HBM.
// ---------------------------------------------------------------------------
__global__ __launch_bounds__(256) void k_uchains(const float* __restrict__ xs,
                                                 const unsigned short* __restrict__ Mb,
                                                 const float* __restrict__ fw0,
                                                 float* __restrict__ FW) {
    __shared__ float Ulds[256][68];           // +4 pad
    const int t = threadIdx.x, lane = t & 63, wid = t >> 6;
    const int l15 = lane & 15, l4 = (lane >> 4) & 3;
    const int j0 = blockIdx.x * 64;

    bf16x8 bfr[4][4];                         // [kk][nf], static-indexed
#pragma unroll
    for (int kk = 0; kk < 4; ++kk)
#pragma unroll
        for (int nf = 0; nf < 4; ++nf)
            bfr[kk][nf] = *reinterpret_cast<const bf16x8*>(
                Mb + (size_t)(j0 + nf * 16 + l15) * IN_DIM + kk * 32 + l4 * 8);

#pragma unroll 1
    for (int ib = 0; ib < 4; ++ib) {
        const int i0 = wid * 64 + ib * 16;
        f32x4 acc[4];
#pragma unroll
        for (int nf = 0; nf < 4; ++nf) acc[nf] = (f32x4){0.f, 0.f, 0.f, 0.f};
#pragma unroll
        for (int kk = 0; kk < 4; ++kk) {
            const float* xp = xs + (size_t)(i0 + l15) * IN_DIM + kk * 32 + l4 * 8;
            f32x4 x0 = *reinterpret_cast<const f32x4*>(xp);
            f32x4 x1 = *reinterpret_cast<const f32x4*>(xp + 4);
            union { bf16x8 v; unsigned short s[8]; } af;
            af.s[0] = f2bf(x0.x); af.s[1] = f2bf(x0.y);
            af.s[2] = f2bf(x0.z); af.s[3] = f2bf(x0.w);
            af.s[4] = f2bf(x1.x); af.s[5] = f2bf(x1.y);
            af.s[6] = f2bf(x1.z); af.s[7] = f2bf(x1.w);
#pragma unroll
            for (int nf = 0; nf < 4; ++nf)
                acc[nf] = __builtin_amdgcn_mfma_f32_16x16x32_bf16(af.v, bfr[kk][nf], acc[nf], 0, 0, 0);
        }
#pragma unroll
        for (int nf = 0; nf < 4; ++nf)
#pragma unroll
            for (int r = 0; r < 4; ++r)
                Ulds[i0 + l4 * 4 + r][nf * 16 + l15] = acc[nf][r];
    }
    __syncthreads();

    if (wid == 0) {
        const int j = j0 + lane;
        float fw = fw0[j];
        float* fp = FW + j;
#pragma unroll 8
        for (int i = 0; i < BATCH; ++i) {
            float u = Ulds[i][lane];
            float z = 10.0f * (fw + u - 0.5f);
            fw = 1.0f / (1.0f + __expf(-z));
            fp[(size_t)i * NFW] = fw;
        }
    }
}

// ---------------------------------------------------------------------------
// Kernel 4: preds. Block per i: h = relu(fw1 @ xs_i), out[i] = fw2 . h.
// ---------------------------------------------------------------------------
__global__ __launch_bounds__(256) void k_preds(const float* __restrict__ FW,
                                               const float* __restrict__ xs,
                                               float* __restrict__ out) {
    __shared__ float xsh[IN_DIM];
    __shared__ float hsh[HID];
    const int i = blockIdx.x, t = threadIdx.x;
    if (t < 32) {
        f32x4 v = *reinterpret_cast<const f32x4*>(xs + (size_t)i * IN_DIM + t * 4);
        xsh[t*4+0] = v.x; xsh[t*4+1] = v.y; xsh[t*4+2] = v.z; xsh[t*4+3] = v.w;
    }
    __syncthreads();
    const int k = t >> 2, q = t & 3;
    const float* fr = FW + (size_t)i * NFW + k * IN_DIM + q * 32;
    float p = 0.f;
#pragma unroll
    for (int m = 0; m < 8; ++m) {
        f32x4 v = *reinterpret_cast<const f32x4*>(fr + m * 4);
        const int d = q * 32 + m * 4;
        p += v.x * xsh[d] + v.y * xsh[d+1] + v.z * xsh[d+2] + v.w * xsh[d+3];
    }
    p += __shfl_xor(p, 1);
    p += __shfl_xor(p, 2);
    if (q == 0) hsh[k] = fmaxf(p, 0.f);
    __syncthreads();
    if (t < 64) {
        float v = FW[(size_t)i * NFW + IN_DIM * HID + t] * hsh[t];
        v += __shfl_xor(v, 1);  v += __shfl_xor(v, 2);  v += __shfl_xor(v, 4);
        v += __shfl_xor(v, 8);  v += __shfl_xor(v, 16); v += __shfl_xor(v, 32);
        if (t == 0) out[i] = v;
    }
}

// ---------------------------------------------------------------------------
// Workspace layout (~40.2 MiB):
//   W1T  bf16 :  4,227,072 B @ 0
//   Mpart f32 : 25,362,432 B @  4,227,072   (6 x 8256 x 128)
//   Mb   bf16 :  2,113,536 B @ 29,589,504
//   FW   f32  :  8,454,144 B @ 31,703,040
// ---------------------------------------------------------------------------
extern "C" void kernel_launch(void* const* d_in, const int* in_sizes, int n_in,
                              void* d_out, int out_size, void* d_ws, size_t ws_size,
                              hipStream_t stream) {
    const float* x   = (const float*)d_in[0];   // (256,1,128)
    const float* W1  = (const float*)d_in[1];   // (16512,128)
    const float* W2  = (const float*)d_in[2];   // (8256,16512)
    const float* fw0 = (const float*)d_in[3];   // (8256,)
    float* out = (float*)d_out;                 // 256 f32

    char* ws = (char*)d_ws;
    unsigned short* W1T   = (unsigned short*)(ws);
    float*          Mpart = (float*)(ws + 4227072);
    unsigned short* Mb    = (unsigned short*)(ws + 29589504);
    float*          FW    = (float*)(ws + 31703040);

    hipLaunchKernelGGL(k_prep_w1t, dim3(258),    dim3(256), 0, stream, W1, W1T);
    hipLaunchKernelGGL(k_gemm_M,   dim3(GRID_M), dim3(256), 0, stream, W2, W1T, Mpart);
    hipLaunchKernelGGL(k_reduce_M, dim3(1032),   dim3(256), 0, stream, Mpart, Mb);
    hipLaunchKernelGGL(k_uchains,  dim3(129),    dim3(256), 0, stream, x, Mb, fw0, FW);
    hipLaunchKernelGGL(k_preds,    dim3(256),    dim3(256), 0, stream, FW, x, out);
}